// Round 1
// baseline (2931.163 us; speedup 1.0000x reference)
//
#include <hip/hip_runtime.h>
#include <hip/hip_bf16.h>
#include <math.h>

#define NPTS   2048
#define BATCH  16
#define EPS    0.0025f          // blur=0.05, p=2 -> eps = 0.05^2
#define INV_EPS 400.0f
#define LOG2E  1.4426950408889634f
#define LN2    0.6931471805599453f
#define LN_N   7.6246189861593985f   // ln(2048)

__device__ __forceinline__ float exp2fast(float x) { return __builtin_amdgcn_exp2f(x); }
__device__ __forceinline__ float log2fast(float x) { return __builtin_amdgcn_logf(x); }

// One Sinkhorn half-update: for each row n (over Xpts), reduce over all cols m
// (over Ypts) of one batch:  out[n] = eps*(ln N - ln2 * LSE2_m(arg2))
// where arg2 = ((Gin[m] - 0.5*(xx+yy-2*x.y)) / eps) * log2(e).
// Per-row term -0.5*xx/eps*log2e is folded in after the reduction.
__global__ __launch_bounds__(256, 4) void sink_update(
    const float* __restrict__ Xpts,   // rows side  [B][N][3]
    const float* __restrict__ Ypts,   // cols side  [B][M][3]
    const float* __restrict__ Gin,    // [B][M] current potential on cols side
    float* __restrict__ Fout)         // [B][N] updated potential on rows side
{
    __shared__ float4 P[NPTS];        // (y0*SC, y1*SC, y2*SC, (g-0.5*yy)*SC)
    const int b    = blockIdx.y;
    const int tile = blockIdx.x;
    const int tid  = threadIdx.x;
    const float SC = INV_EPS * LOG2E;

    const float* Yb = Ypts + (size_t)b * NPTS * 3;
    const float* Gb = Gin  + (size_t)b * NPTS;
    for (int m = tid; m < NPTS; m += 256) {
        float y0 = Yb[3*m], y1 = Yb[3*m+1], y2 = Yb[3*m+2];
        float g  = Gb[m];
        float yy = y0*y0 + y1*y1 + y2*y2;
        P[m] = make_float4(y0*SC, y1*SC, y2*SC, (g - 0.5f*yy)*SC);
    }
    __syncthreads();

    const int sub = tid & 7;          // 8 lanes cooperate on one row
    const int r   = tid >> 3;         // 32 rows per block
    const int row = tile * 32 + r;
    const float* xp = Xpts + ((size_t)b * NPTS + row) * 3;
    const float x0 = xp[0], x1 = xp[1], x2 = xp[2];
    const float xx = x0*x0 + x1*x1 + x2*x2;

    // two independent online-LSE accumulators for ILP
    float mx0 = -3.0e38f, mx1 = -3.0e38f, s0 = 0.0f, s1 = 0.0f;
    for (int k = sub; k < NPTS; k += 16) {
        float4 p = P[k];
        float4 q = P[k + 8];
        float t0 = fmaf(x0, p.x, fmaf(x1, p.y, fmaf(x2, p.z, p.w)));
        float t1 = fmaf(x0, q.x, fmaf(x1, q.y, fmaf(x2, q.z, q.w)));
        float nm0 = fmaxf(mx0, t0);
        s0 = fmaf(s0, exp2fast(mx0 - nm0), exp2fast(t0 - nm0));
        mx0 = nm0;
        float nm1 = fmaxf(mx1, t1);
        s1 = fmaf(s1, exp2fast(mx1 - nm1), exp2fast(t1 - nm1));
        mx1 = nm1;
    }
    // merge the two accumulators
    float mx = fmaxf(mx0, mx1);
    float s  = fmaf(s0, exp2fast(mx0 - mx), s1 * exp2fast(mx1 - mx));
    // merge across the 8 cooperating lanes
    #pragma unroll
    for (int d = 1; d < 8; d <<= 1) {
        float om = __shfl_xor(mx, d);
        float os = __shfl_xor(s,  d);
        float nm = fmaxf(mx, om);
        s  = fmaf(s, exp2fast(mx - nm), os * exp2fast(om - nm));
        mx = nm;
    }
    if (sub == 0) {
        float a2   = -0.5f * xx * SC;              // per-row constant (log2 units)
        float lse2 = a2 + mx + log2fast(s);        // log2(sum exp2(arg2))
        Fout[(size_t)b * NPTS + row] = EPS * (LN_N - LN2 * lse2);
    }
}

// Chamfer direction: for each row over Xpts, min over Ypts of squared dist,
// clamped at 0; block-reduced then one atomicAdd into acc.
__global__ __launch_bounds__(256, 4) void chamfer_min(
    const float* __restrict__ Xpts, const float* __restrict__ Ypts,
    float* __restrict__ acc)
{
    __shared__ float4 P[NPTS];        // (y0, y1, y2, yy)
    __shared__ float blocksum;
    const int b = blockIdx.y, tile = blockIdx.x, tid = threadIdx.x;
    if (tid == 0) blocksum = 0.0f;
    const float* Yb = Ypts + (size_t)b * NPTS * 3;
    for (int m = tid; m < NPTS; m += 256) {
        float y0 = Yb[3*m], y1 = Yb[3*m+1], y2 = Yb[3*m+2];
        P[m] = make_float4(y0, y1, y2, y0*y0 + y1*y1 + y2*y2);
    }
    __syncthreads();

    const int sub = tid & 7, r = tid >> 3, row = tile * 32 + r;
    const float* xp = Xpts + ((size_t)b * NPTS + row) * 3;
    const float x0 = xp[0], x1 = xp[1], x2 = xp[2];
    const float xx = x0*x0 + x1*x1 + x2*x2;

    float mn = 3.0e38f;
    for (int k = sub; k < NPTS; k += 8) {
        float4 p = P[k];
        float t = fmaf(x0, p.x, fmaf(x1, p.y, x2 * p.z));
        float d = fmaf(-2.0f, t, xx + p.w);       // xx + yy - 2*x.y
        mn = fminf(mn, d);
    }
    #pragma unroll
    for (int d = 1; d < 8; d <<= 1) mn = fminf(mn, __shfl_xor(mn, d));
    if (sub == 0) atomicAdd(&blocksum, fmaxf(mn, 0.0f));
    __syncthreads();
    if (tid == 0) atomicAdd(acc, blocksum);
}

__global__ void finalize(const float* __restrict__ F, const float* __restrict__ G,
                         const float* __restrict__ acc, float* __restrict__ out)
{
    const int b = blockIdx.x, tid = threadIdx.x;
    float sf = 0.0f, sg = 0.0f;
    for (int i = tid; i < NPTS; i += 256) {
        sf += F[(size_t)b * NPTS + i];
        sg += G[(size_t)b * NPTS + i];
    }
    #pragma unroll
    for (int d = 1; d < 64; d <<= 1) { sf += __shfl_xor(sf, d); sg += __shfl_xor(sg, d); }
    __shared__ float wf[4], wg[4];
    const int w = tid >> 6;
    if ((tid & 63) == 0) { wf[w] = sf; wg[w] = sg; }
    __syncthreads();
    if (tid == 0) {
        float tf = wf[0] + wf[1] + wf[2] + wf[3];
        float tg = wg[0] + wg[1] + wg[2] + wg[3];
        float emd = (tf + tg) * (1.0f / NPTS);                 // mean f + mean g
        float cd  = acc[0] * (1.0f / (BATCH * NPTS));          // both directions summed
        out[b] = 0.5f * cd + 0.5f * emd;
    }
}

extern "C" void kernel_launch(void* const* d_in, const int* in_sizes, int n_in,
                              void* d_out, int out_size, void* d_ws, size_t ws_size,
                              hipStream_t stream)
{
    const float* Xtrue = (const float*)d_in[0];   // y_true: rows of D
    const float* Ypred = (const float*)d_in[1];   // y_pred: cols of D
    float* F   = (float*)d_ws;                    // [16][2048]
    float* G   = F + BATCH * NPTS;                // [16][2048]
    float* acc = G + BATCH * NPTS;                // 1 float (chamfer sum)

    hipMemsetAsync(G,   0, BATCH * NPTS * sizeof(float), stream);
    hipMemsetAsync(acc, 0, sizeof(float), stream);

    dim3 grid(NPTS / 32, BATCH), blk(256);
    chamfer_min<<<grid, blk, 0, stream>>>(Xtrue, Ypred, acc);
    chamfer_min<<<grid, blk, 0, stream>>>(Ypred, Xtrue, acc);

    for (int it = 0; it < 50; ++it) {
        sink_update<<<grid, blk, 0, stream>>>(Xtrue, Ypred, G, F);  // f from g
        sink_update<<<grid, blk, 0, stream>>>(Ypred, Xtrue, F, G);  // g from f
    }
    finalize<<<dim3(BATCH), blk, 0, stream>>>(F, G, acc, (float*)d_out);
}

// Round 2
// 2061.984 us; speedup vs baseline: 1.4215x; 1.4215x over previous
//
#include <hip/hip_runtime.h>
#include <hip/hip_bf16.h>
#include <math.h>

#define NPTS   2048
#define BATCH  16
#define EPS    0.0025f          // blur=0.05, p=2 -> eps = 0.05^2
#define INV_EPS 400.0f
#define LOG2E  1.4426950408889634f
#define LN2    0.6931471805599453f
#define LN_N   7.6246189861593985f   // ln(2048)

#define ROWS_PER_THREAD 4
#define LANES_PER_ROW   16
#define ROWS_PER_BLOCK  64        // (256/16 groups) * 4 rows
#define GRID_X          (NPTS / ROWS_PER_BLOCK)   // 32

__device__ __forceinline__ float exp2fast(float x) { return __builtin_amdgcn_exp2f(x); }
__device__ __forceinline__ float log2fast(float x) { return __builtin_amdgcn_logf(x); }

// One Sinkhorn half-update, 4 rows per thread, 16 lanes per row.
// out[n] = eps*(ln N - ln2 * lse2)   where
// lse2 = log2 sum_m exp2( (Gin[m] - 0.5*|x_n - y_m|^2) / eps * log2(e) ).
// Gin == nullptr means g == 0 (first iteration), avoiding a memset.
__global__ __launch_bounds__(256, 4) void sink_update(
    const float* __restrict__ Xpts,   // rows side  [B][N][3]
    const float* __restrict__ Ypts,   // cols side  [B][M][3]
    const float* __restrict__ Gin,    // [B][M] potential on cols side (or null)
    float* __restrict__ Fout)         // [B][N] updated potential on rows side
{
    __shared__ float4 P[NPTS];        // (y0*SC, y1*SC, y2*SC, (g-0.5*yy)*SC)
    const int b    = blockIdx.y;
    const int tile = blockIdx.x;
    const int tid  = threadIdx.x;
    const float SC = INV_EPS * LOG2E;

    const int sub  = tid & (LANES_PER_ROW - 1);
    const int grp  = tid >> 4;                       // 16 row-groups
    const int row0 = tile * ROWS_PER_BLOCK + grp * ROWS_PER_THREAD;

    // issue x loads early (L2-resident)
    const float* xp = Xpts + ((size_t)b * NPTS + row0) * 3;
    float x0[ROWS_PER_THREAD], x1[ROWS_PER_THREAD], x2[ROWS_PER_THREAD];
    float a2[ROWS_PER_THREAD], mx[ROWS_PER_THREAD], s[ROWS_PER_THREAD];
    #pragma unroll
    for (int rr = 0; rr < ROWS_PER_THREAD; ++rr) {
        x0[rr] = xp[3*rr]; x1[rr] = xp[3*rr+1]; x2[rr] = xp[3*rr+2];
    }

    const float* Yb = Ypts + (size_t)b * NPTS * 3;
    if (Gin) {
        const float* Gb = Gin + (size_t)b * NPTS;
        for (int m = tid; m < NPTS; m += 256) {
            float y0 = Yb[3*m], y1 = Yb[3*m+1], y2 = Yb[3*m+2];
            float yy = y0*y0 + y1*y1 + y2*y2;
            P[m] = make_float4(y0*SC, y1*SC, y2*SC, (Gb[m] - 0.5f*yy)*SC);
        }
    } else {
        for (int m = tid; m < NPTS; m += 256) {
            float y0 = Yb[3*m], y1 = Yb[3*m+1], y2 = Yb[3*m+2];
            float yy = y0*y0 + y1*y1 + y2*y2;
            P[m] = make_float4(y0*SC, y1*SC, y2*SC, -0.5f*yy*SC);
        }
    }

    #pragma unroll
    for (int rr = 0; rr < ROWS_PER_THREAD; ++rr) {
        a2[rr] = -0.5f * (x0[rr]*x0[rr] + x1[rr]*x1[rr] + x2[rr]*x2[rr]) * SC;
        mx[rr] = -3.0e38f;
        s[rr]  = 0.0f;
    }
    __syncthreads();

    // 4-column chunks: one chunk-max -> 5 exps per 4 columns per row
    for (int k = sub; k < NPTS; k += 64) {
        float4 c0 = P[k];
        float4 c1 = P[k + 16];
        float4 c2 = P[k + 32];
        float4 c3 = P[k + 48];
        #pragma unroll
        for (int rr = 0; rr < ROWS_PER_THREAD; ++rr) {
            float t0 = fmaf(x0[rr], c0.x, fmaf(x1[rr], c0.y, fmaf(x2[rr], c0.z, c0.w)));
            float t1 = fmaf(x0[rr], c1.x, fmaf(x1[rr], c1.y, fmaf(x2[rr], c1.z, c1.w)));
            float t2 = fmaf(x0[rr], c2.x, fmaf(x1[rr], c2.y, fmaf(x2[rr], c2.z, c2.w)));
            float t3 = fmaf(x0[rr], c3.x, fmaf(x1[rr], c3.y, fmaf(x2[rr], c3.z, c3.w)));
            float mc = fmaxf(fmaxf(t0, t1), fmaxf(t2, t3));
            float nm = fmaxf(mx[rr], mc);
            float er = exp2fast(mx[rr] - nm);
            float e0 = exp2fast(t0 - nm);
            float e1 = exp2fast(t1 - nm);
            float e2 = exp2fast(t2 - nm);
            float e3 = exp2fast(t3 - nm);
            s[rr]  = fmaf(s[rr], er, (e0 + e1) + (e2 + e3));
            mx[rr] = nm;
        }
    }

    // merge across the 16 cooperating lanes
    #pragma unroll
    for (int d = 1; d < LANES_PER_ROW; d <<= 1) {
        #pragma unroll
        for (int rr = 0; rr < ROWS_PER_THREAD; ++rr) {
            float om = __shfl_xor(mx[rr], d);
            float os = __shfl_xor(s[rr],  d);
            float nm = fmaxf(mx[rr], om);
            s[rr]  = fmaf(s[rr], exp2fast(mx[rr] - nm), os * exp2fast(om - nm));
            mx[rr] = nm;
        }
    }
    if (sub == 0) {
        float* Fb = Fout + (size_t)b * NPTS + row0;
        #pragma unroll
        for (int rr = 0; rr < ROWS_PER_THREAD; ++rr) {
            float lse2 = a2[rr] + mx[rr] + log2fast(s[rr]);
            Fb[rr] = EPS * (LN_N - LN2 * lse2);
        }
    }
}

// Chamfer direction: min over cols of squared dist per row, 4 rows/thread.
// Per-block partial sum written to part[] (no atomics -> deterministic).
__global__ __launch_bounds__(256, 4) void chamfer_min(
    const float* __restrict__ Xpts, const float* __restrict__ Ypts,
    float* __restrict__ part)
{
    __shared__ float4 P[NPTS];        // (y0, y1, y2, yy)
    __shared__ float gsum[16];
    const int b = blockIdx.y, tile = blockIdx.x, tid = threadIdx.x;
    const int sub = tid & (LANES_PER_ROW - 1);
    const int grp = tid >> 4;
    const int row0 = tile * ROWS_PER_BLOCK + grp * ROWS_PER_THREAD;

    const float* xp = Xpts + ((size_t)b * NPTS + row0) * 3;
    float x0[ROWS_PER_THREAD], x1[ROWS_PER_THREAD], x2[ROWS_PER_THREAD], xx[ROWS_PER_THREAD];
    #pragma unroll
    for (int rr = 0; rr < ROWS_PER_THREAD; ++rr) {
        x0[rr] = xp[3*rr]; x1[rr] = xp[3*rr+1]; x2[rr] = xp[3*rr+2];
        xx[rr] = x0[rr]*x0[rr] + x1[rr]*x1[rr] + x2[rr]*x2[rr];
    }

    const float* Yb = Ypts + (size_t)b * NPTS * 3;
    for (int m = tid; m < NPTS; m += 256) {
        float y0 = Yb[3*m], y1 = Yb[3*m+1], y2 = Yb[3*m+2];
        P[m] = make_float4(y0, y1, y2, y0*y0 + y1*y1 + y2*y2);
    }
    __syncthreads();

    float mn[ROWS_PER_THREAD] = {3.0e38f, 3.0e38f, 3.0e38f, 3.0e38f};
    for (int k = sub; k < NPTS; k += 64) {
        float4 c0 = P[k];
        float4 c1 = P[k + 16];
        float4 c2 = P[k + 32];
        float4 c3 = P[k + 48];
        #pragma unroll
        for (int rr = 0; rr < ROWS_PER_THREAD; ++rr) {
            float t0 = fmaf(x0[rr], c0.x, fmaf(x1[rr], c0.y, x2[rr]*c0.z));
            float t1 = fmaf(x0[rr], c1.x, fmaf(x1[rr], c1.y, x2[rr]*c1.z));
            float t2 = fmaf(x0[rr], c2.x, fmaf(x1[rr], c2.y, x2[rr]*c2.z));
            float t3 = fmaf(x0[rr], c3.x, fmaf(x1[rr], c3.y, x2[rr]*c3.z));
            float d0 = fmaf(-2.0f, t0, xx[rr] + c0.w);
            float d1 = fmaf(-2.0f, t1, xx[rr] + c1.w);
            float d2 = fmaf(-2.0f, t2, xx[rr] + c2.w);
            float d3 = fmaf(-2.0f, t3, xx[rr] + c3.w);
            mn[rr] = fminf(fminf(fminf(mn[rr], d0), fminf(d1, d2)), d3);
        }
    }
    #pragma unroll
    for (int d = 1; d < LANES_PER_ROW; d <<= 1) {
        #pragma unroll
        for (int rr = 0; rr < ROWS_PER_THREAD; ++rr)
            mn[rr] = fminf(mn[rr], __shfl_xor(mn[rr], d));
    }
    if (sub == 0) {
        gsum[grp] = fmaxf(mn[0], 0.0f) + fmaxf(mn[1], 0.0f)
                  + fmaxf(mn[2], 0.0f) + fmaxf(mn[3], 0.0f);
    }
    __syncthreads();
    if (tid == 0) {
        float t = 0.0f;
        #pragma unroll
        for (int i = 0; i < 16; ++i) t += gsum[i];
        part[blockIdx.y * GRID_X + blockIdx.x] = t;
    }
}

__global__ void finalize(const float* __restrict__ F, const float* __restrict__ G,
                         const float* __restrict__ part, float* __restrict__ out)
{
    const int b = blockIdx.x, tid = threadIdx.x;
    float sf = 0.0f, sg = 0.0f, sc = 0.0f;
    for (int i = tid; i < NPTS; i += 256) {
        sf += F[(size_t)b * NPTS + i];
        sg += G[(size_t)b * NPTS + i];
    }
    for (int i = tid; i < 2 * GRID_X * BATCH; i += 256) sc += part[i];
    #pragma unroll
    for (int d = 1; d < 64; d <<= 1) {
        sf += __shfl_xor(sf, d); sg += __shfl_xor(sg, d); sc += __shfl_xor(sc, d);
    }
    __shared__ float wf[4], wg[4], wc[4];
    const int w = tid >> 6;
    if ((tid & 63) == 0) { wf[w] = sf; wg[w] = sg; wc[w] = sc; }
    __syncthreads();
    if (tid == 0) {
        float tf = wf[0] + wf[1] + wf[2] + wf[3];
        float tg = wg[0] + wg[1] + wg[2] + wg[3];
        float tc = wc[0] + wc[1] + wc[2] + wc[3];
        float emd = (tf + tg) * (1.0f / NPTS);                 // mean f + mean g
        float cd  = tc * (1.0f / (BATCH * NPTS));              // both directions
        out[b] = 0.5f * cd + 0.5f * emd;
    }
}

extern "C" void kernel_launch(void* const* d_in, const int* in_sizes, int n_in,
                              void* d_out, int out_size, void* d_ws, size_t ws_size,
                              hipStream_t stream)
{
    const float* Xtrue = (const float*)d_in[0];   // y_true: rows of D
    const float* Ypred = (const float*)d_in[1];   // y_pred: cols of D
    float* F    = (float*)d_ws;                   // [16][2048]
    float* G    = F + BATCH * NPTS;               // [16][2048]
    float* part = G + BATCH * NPTS;               // [2 * 32 * 16]

    dim3 grid(GRID_X, BATCH), blk(256);
    chamfer_min<<<grid, blk, 0, stream>>>(Xtrue, Ypred, part);
    chamfer_min<<<grid, blk, 0, stream>>>(Ypred, Xtrue, part + GRID_X * BATCH);

    // iteration 0: g == 0 handled by nullptr (no memset needed)
    sink_update<<<grid, blk, 0, stream>>>(Xtrue, Ypred, nullptr, F);
    sink_update<<<grid, blk, 0, stream>>>(Ypred, Xtrue, F, G);
    for (int it = 1; it < 50; ++it) {
        sink_update<<<grid, blk, 0, stream>>>(Xtrue, Ypred, G, F);  // f from g
        sink_update<<<grid, blk, 0, stream>>>(Ypred, Xtrue, F, G);  // g from f
    }
    finalize<<<dim3(BATCH), blk, 0, stream>>>(F, G, part, (float*)d_out);
}